// Round 9
// baseline (597.499 us; speedup 1.0000x reference)
//
#include <hip/hip_runtime.h>
#include <hip/hip_bf16.h>

// Problem constants
#define B_ 16
#define T_ 1024
#define D_ 1024

using frag8  = __attribute__((ext_vector_type(8))) short;   // 8 bf16 (4 VGPRs)
using f32x4  = __attribute__((ext_vector_type(4))) float;   // 4 fp32 acc
using u16x8  = __attribute__((ext_vector_type(8))) unsigned short; // 16B chunk

__device__ inline unsigned short f2bf(float f) {
    union { float f; unsigned u; } v; v.f = f;
    unsigned r = v.u + 0x7FFF + ((v.u >> 16) & 1);   // round-nearest-even
    return (unsigned short)(r >> 16);
}
__device__ inline float bf2f(unsigned short u) {
    union { unsigned u; float f; } v; v.u = ((unsigned)u) << 16;
    return v.f;
}

// ---------------------------------------------------------------------------
// L1 "prep": one launch, all work that depends only on the raw inputs.
//  [0,128)      small weight-product GEMMs (fp32 staged + converted in LDS):
//                 z=0: NT[f][e]=sum_d Wq[f][d]Wk[e][d] -> ntb
//                 z=1: M [q][e]=sum_d Wfc[q][d]Wv[e][d] -> mb
//  [128,4224)   cast Wq/Wk/Wv/Wfc fp32 -> bf16 (row-major, k-major use)
//  [4224,5248)  wvec: w1=Wk·bq, w2=Wq·bk, cvec=Wfc·bv, bkbq=bk·bq
//               (y==3 block 0 also zeroes the 16 finalize counters)
//  [5248,9344)  cast x fp32 -> bf16
// ---------------------------------------------------------------------------
__global__ __launch_bounds__(256)
void prep(const float* __restrict__ x,
          const float* __restrict__ Wq, const float* __restrict__ Wk,
          const float* __restrict__ Wv, const float* __restrict__ Wfc,
          const float* __restrict__ bq, const float* __restrict__ bk,
          const float* __restrict__ bv,
          unsigned short* __restrict__ xb,
          unsigned short* __restrict__ wqb, unsigned short* __restrict__ wkb,
          unsigned short* __restrict__ wvb, unsigned short* __restrict__ wfcb,
          unsigned short* __restrict__ ntb, unsigned short* __restrict__ mb,
          float* __restrict__ w1, float* __restrict__ w2,
          float* __restrict__ cvec, float* __restrict__ bkbq,
          int* __restrict__ ctr) {
    __shared__ __align__(16) unsigned char smem[16384];
    const int bx  = blockIdx.x;
    const int tid = threadIdx.x, lane = tid & 63, wave = tid >> 6;

    if (bx < 128) {
        // ---- small GEMM, fp32 inputs converted during staging ----
        unsigned short* As = (unsigned short*)smem;
        unsigned short* Bs = As + 4096;
        const int z = bx >> 6, rem = bx & 63;
        const int n0 = (rem & 7) * 128, m0 = (rem >> 3) * 128;
        const float* A  = z ? Wfc : Wq;
        const float* Bm = z ? Wv  : Wk;
        unsigned short* out = z ? mb : ntb;

        const int wm = (wave >> 1) * 64, wn = (wave & 1) * 64;
        f32x4 acc[4][4];
#pragma unroll
        for (int i = 0; i < 4; i++)
#pragma unroll
            for (int j = 0; j < 4; j++) acc[i][j] = (f32x4){0.f, 0.f, 0.f, 0.f};

        const int ak = tid & 31, am = tid >> 5;
        const int fr = lane & 15, fk = (lane >> 4) * 8;
        for (int k0 = 0; k0 < D_; k0 += 32) {
#pragma unroll
            for (int it = 0; it < 16; ++it) {
                int m = am + it * 8;
                As[m * 32 + ak] = f2bf(A [(size_t)(m0 + m) * D_ + k0 + ak]);
                Bs[m * 32 + ak] = f2bf(Bm[(size_t)(n0 + m) * D_ + k0 + ak]);
            }
            __syncthreads();
            frag8 af[4], bff[4];
#pragma unroll
            for (int t = 0; t < 4; ++t) {
                af[t]  = *(const frag8*)&As[(wm + t * 16 + fr) * 32 + fk];
                bff[t] = *(const frag8*)&Bs[(wn + t * 16 + fr) * 32 + fk];
            }
#pragma unroll
            for (int i = 0; i < 4; i++)
#pragma unroll
                for (int j = 0; j < 4; j++)
                    acc[i][j] = __builtin_amdgcn_mfma_f32_16x16x32_bf16(
                        af[i], bff[j], acc[i][j], 0, 0, 0);
            __syncthreads();
        }
        const int col = lane & 15, rbase = (lane >> 4) * 4;
#pragma unroll
        for (int i = 0; i < 4; i++)
#pragma unroll
            for (int j = 0; j < 4; j++) {
                int gn = n0 + wn + j * 16 + col;
#pragma unroll
                for (int r = 0; r < 4; r++) {
                    int gm = m0 + wm + i * 16 + rbase + r;
                    out[(size_t)gm * D_ + gn] = f2bf(acc[i][j][r]);
                }
            }
        return;
    }
    if (bx < 4224) {
        // ---- weight casts ----
        const int w = (bx - 128) >> 10;
        const float* src = (w == 0) ? Wq : (w == 1) ? Wk : (w == 2) ? Wv : Wfc;
        unsigned short* dst = (w == 0) ? wqb : (w == 1) ? wkb : (w == 2) ? wvb : wfcb;
        int i = ((bx - 128) & 1023) * 256 + tid;
        float4 v = ((const float4*)src)[i];
        ushort4 o;
        o.x = f2bf(v.x); o.y = f2bf(v.y); o.z = f2bf(v.z); o.w = f2bf(v.w);
        ((ushort4*)dst)[i] = o;
        return;
    }
    if (bx < 5248) {
        // ---- wvec ----
        const int b2 = bx - 4224, y = b2 >> 8, xblk = b2 & 255;
        float* sm = (float*)smem;
        if (y == 3) {
            if (xblk != 0) return;
            if (tid < B_) ctr[tid] = 0;           // zero finalize counters
            float s = 0.f;
#pragma unroll
            for (int p = 0; p < 4; ++p) { int i = tid + p * 256; s += bk[i] * bq[i]; }
#pragma unroll
            for (int off = 32; off; off >>= 1) s += __shfl_down(s, off);
            if (lane == 0) sm[wave] = s;
            __syncthreads();
            if (tid == 0) bkbq[0] = sm[0] + sm[1] + sm[2] + sm[3];
            return;
        }
        const float* Wsrc; const float* bvv; float* outp;
        if (y == 0)      { Wsrc = Wk;  bvv = bq; outp = w1; }
        else if (y == 1) { Wsrc = Wq;  bvv = bk; outp = w2; }
        else             { Wsrc = Wfc; bvv = bv; outp = cvec; }
        const int row = xblk * 4 + wave;
        const float* r = Wsrc + (size_t)row * D_;
        float s = 0.f;
#pragma unroll
        for (int it = 0; it < 4; ++it) {
            float4 a = *(const float4*)&r[it * 256 + lane * 4];
            float4 b = *(const float4*)&bvv[it * 256 + lane * 4];
            s += a.x * b.x + a.y * b.y + a.z * b.z + a.w * b.w;
        }
#pragma unroll
        for (int off = 32; off; off >>= 1) s += __shfl_down(s, off);
        if (lane == 0) outp[row] = s;
        return;
    }
    // ---- x cast: 4096 blocks x 1024 float4 each ----
    {
        const int blk = bx - 5248;
#pragma unroll
        for (int p = 0; p < 4; ++p) {
            int i = blk * 1024 + p * 256 + tid;
            float4 v = ((const float4*)x)[i];
            ushort4 o;
            o.x = f2bf(v.x); o.y = f2bf(v.y); o.z = f2bf(v.z); o.w = f2bf(v.w);
            ((ushort4*)xb)[i] = o;
        }
    }
}

// ---------------------------------------------------------------------------
// L2: fused P/G GEMM + uv row-dots in one launch (grid 6144).
//  [0,2048): GEMM, A = xb (M=16384, K=1024, N=1024):
//   z=0: P[i][f] = x·NT^T -> pb (row-major bf16)
//   z=1: G[i][q] = x·M^T + c -> gbuf fragment-swizzled (16B chunks/thread)
//   XCD swizzle: each XCD owns 16 m-blocks (4 MB of x, L2-resident).
//  [2048,6144): uv blocks — u[i]=x_i·w1, v[i]=x_i·w2+bkbq (4 rows/block).
// ---------------------------------------------------------------------------
__global__ __launch_bounds__(256)
void pg_gemm(const unsigned short* __restrict__ xb,
             const unsigned short* __restrict__ ntb,
             const unsigned short* __restrict__ mb,
             const float* __restrict__ cvec,
             const float* __restrict__ w1, const float* __restrict__ w2,
             const float* __restrict__ bkbq,
             unsigned short* __restrict__ pb,
             unsigned short* __restrict__ gbuf,
             float* __restrict__ u, float* __restrict__ v) {
    __shared__ __align__(16) unsigned char smem[16384];
    const int l   = blockIdx.x;
    const int tid = threadIdx.x, lane = tid & 63, wave = tid >> 6;

    if (l >= 2048) {
        // ---- uv path ----
        float* s1 = (float*)smem;
        float* s2 = s1 + 1024;
#pragma unroll
        for (int p = 0; p < 4; ++p) {
            int i = tid + p * 256;
            s1[i] = w1[i]; s2[i] = w2[i];
        }
        __syncthreads();
        const int row = (l - 2048) * 4 + wave;
        const unsigned short* xr = xb + (size_t)row * D_;
        float du = 0.f, dv = 0.f;
#pragma unroll
        for (int it = 0; it < 2; ++it) {
            const int base = it * 512 + lane * 8;
            ushort4 a0 = *(const ushort4*)&xr[base];
            ushort4 a1 = *(const ushort4*)&xr[base + 4];
            float xv[8] = {bf2f(a0.x), bf2f(a0.y), bf2f(a0.z), bf2f(a0.w),
                           bf2f(a1.x), bf2f(a1.y), bf2f(a1.z), bf2f(a1.w)};
            float4 b0 = *(const float4*)&s1[base];
            float4 b1 = *(const float4*)&s1[base + 4];
            float4 c0 = *(const float4*)&s2[base];
            float4 c1 = *(const float4*)&s2[base + 4];
            du += xv[0]*b0.x + xv[1]*b0.y + xv[2]*b0.z + xv[3]*b0.w
                + xv[4]*b1.x + xv[5]*b1.y + xv[6]*b1.z + xv[7]*b1.w;
            dv += xv[0]*c0.x + xv[1]*c0.y + xv[2]*c0.z + xv[3]*c0.w
                + xv[4]*c1.x + xv[5]*c1.y + xv[6]*c1.z + xv[7]*c1.w;
        }
#pragma unroll
        for (int off = 32; off; off >>= 1) {
            du += __shfl_down(du, off);
            dv += __shfl_down(dv, off);
        }
        if (lane == 0) { u[row] = du; v[row] = dv + bkbq[0]; }
        return;
    }

    // ---- GEMM path ----
    unsigned short* As = (unsigned short*)smem;
    unsigned short* Bs = As + 4096;

    const int xcd  = l & 7;
    const int idx  = l >> 3;            // 0..255
    const int mblk = xcd * 16 + (idx & 15);
    const int rest = idx >> 4;          // 0..15
    const int z    = rest >> 3;
    const int nblk = rest & 7;
    const int n0   = nblk * 128;
    const int m0   = mblk * 128;

    const unsigned short* Bm = z ? mb : ntb;
    const int wm = (wave >> 1) * 64, wn = (wave & 1) * 64;

    f32x4 acc[4][4];
#pragma unroll
    for (int i = 0; i < 4; i++)
#pragma unroll
        for (int j = 0; j < 4; j++) acc[i][j] = (f32x4){0.f, 0.f, 0.f, 0.f};

    const int srow = lane >> 2;
    const int sk   = (lane & 3) * 8;
    const int fr = lane & 15, fk = (lane >> 4) * 8;

    for (int k0 = 0; k0 < D_; k0 += 32) {
#pragma unroll
        for (int it = 0; it < 2; ++it) {
            const int rb = wave * 2 + it;
            const int r  = rb * 16 + srow;
            __builtin_amdgcn_global_load_lds(
                (const __attribute__((address_space(1))) unsigned int*)
                    (xb + (size_t)(m0 + r) * D_ + k0 + sk),
                (__attribute__((address_space(3))) unsigned int*)(As + rb * 512),
                16, 0, 0);
            __builtin_amdgcn_global_load_lds(
                (const __attribute__((address_space(1))) unsigned int*)
                    (Bm + (size_t)(n0 + r) * D_ + k0 + sk),
                (__attribute__((address_space(3))) unsigned int*)(Bs + rb * 512),
                16, 0, 0);
        }
        __syncthreads();

        frag8 af[4], bff[4];
#pragma unroll
        for (int t = 0; t < 4; ++t)
            af[t] = *(const frag8*)&As[(wm + t * 16 + fr) * 32 + fk];
#pragma unroll
        for (int t = 0; t < 4; ++t)
            bff[t] = *(const frag8*)&Bs[(wn + t * 16 + fr) * 32 + fk];
#pragma unroll
        for (int i = 0; i < 4; i++)
#pragma unroll
            for (int j = 0; j < 4; j++)
                acc[i][j] = __builtin_amdgcn_mfma_f32_16x16x32_bf16(
                    af[i], bff[j], acc[i][j], 0, 0, 0);
        __syncthreads();
    }

    const int col   = lane & 15;
    const int rbase = (lane >> 4) * 4;
    if (z == 0) {
#pragma unroll
        for (int i = 0; i < 4; i++) {
#pragma unroll
            for (int j = 0; j < 4; j++) {
                int gn = n0 + wn + j * 16 + col;
#pragma unroll
                for (int r = 0; r < 4; r++) {
                    int gm = m0 + wm + i * 16 + rbase + r;
                    pb[(size_t)gm * D_ + gn] = f2bf(acc[i][j][r]);
                }
            }
        }
    } else {
        float bb[4];
#pragma unroll
        for (int j = 0; j < 4; j++) bb[j] = cvec[n0 + wn + j * 16 + col];
        unsigned short* base = gbuf + ((size_t)(mblk * 8 + nblk) << 14) + tid * 8;
#pragma unroll
        for (int c = 0; c < 8; ++c) {
            const int i = c >> 1;
            u16x8 o;
#pragma unroll
            for (int e = 0; e < 8; ++e) {
                const int f  = c * 8 + e;
                const int jj = (f >> 2) & 3;
                const int r  = f & 3;
                o[e] = f2bf(acc[i][jj][r] + bb[jj]);
            }
            *(u16x8*)(base + (size_t)c * 2048) = o;
        }
    }
}

// ---------------------------------------------------------------------------
// L3: score + exp + G-weighted row reduction + LAST-BLOCK FINALIZE.
// S = P·x^T (+u_i+v_j), p = exp(S·scale); deterministic partial stores
// (each slot single-writer).  The 64th block of each b (device-scope
// counter) sums all partials in fixed order and writes out[b] — the
// arithmetic is identical regardless of which block finalizes.
// grid (8,8,16) block 256, XCD swizzle as before.
// ---------------------------------------------------------------------------
__global__ __launch_bounds__(256)
void score_attn(const unsigned short* __restrict__ pbuf,
                const unsigned short* __restrict__ xb,
                const unsigned short* __restrict__ gb,
                const float* __restrict__ u, const float* __restrict__ v,
                float* __restrict__ lpart, float* __restrict__ Apart,
                int* __restrict__ ctr, const float* __restrict__ bfc,
                float* __restrict__ out) {
    __shared__ __align__(16) unsigned short Ks[128 * 32];
    __shared__ __align__(16) unsigned short Qs[128 * 32];
    __shared__ int lastflag;

    const int l   = blockIdx.x + 8 * blockIdx.y + 64 * blockIdx.z;
    const int xcd = l & 7;
    const int uix = l >> 3;            // 0..127
    const int i0b = uix >> 4;          // 0..7  (i0 outer)
    const int mid = uix & 15;
    const int b   = xcd * 2 + (mid >> 3);
    const int j0b = mid & 7;           // j0 inner
    const int i0 = i0b * 128, j0 = j0b * 128;

    const unsigned short* P = pbuf + ((size_t)b * T_ + i0) * D_;
    const unsigned short* X = xb   + ((size_t)b * T_ + j0) * D_;

    const int tid = threadIdx.x, lane = tid & 63, wave = tid >> 6;
    const int wm = (wave >> 1) * 64, wn = (wave & 1) * 64;

    f32x4 accS[4][4];
#pragma unroll
    for (int i = 0; i < 4; i++)
#pragma unroll
        for (int j = 0; j < 4; j++) accS[i][j] = (f32x4){0.f, 0.f, 0.f, 0.f};

    const int srow = lane >> 2;
    const int sk   = (lane & 3) * 8;
    const int fr = lane & 15, fk = (lane >> 4) * 8;

    for (int k0 = 0; k0 < D_; k0 += 32) {
#pragma unroll
        for (int it = 0; it < 2; ++it) {
            const int rb = wave * 2 + it;
            const int r  = rb * 16 + srow;
            __builtin_amdgcn_global_load_lds(
                (const __attribute__((address_space(1))) unsigned int*)
                    (P + (size_t)r * D_ + k0 + sk),
                (__attribute__((address_space(3))) unsigned int*)(Ks + rb * 512),
                16, 0, 0);
            __builtin_amdgcn_global_load_lds(
                (const __attribute__((address_space(1))) unsigned int*)
                    (X + (size_t)r * D_ + k0 + sk),
                (__attribute__((address_space(3))) unsigned int*)(Qs + rb * 512),
                16, 0, 0);
        }
        __syncthreads();

        frag8 af[4], bff[4];
#pragma unroll
        for (int t = 0; t < 4; ++t)
            af[t] = *(const frag8*)&Ks[(wm + t * 16 + fr) * 32 + fk];
#pragma unroll
        for (int t = 0; t < 4; ++t)
            bff[t] = *(const frag8*)&Qs[(wn + t * 16 + fr) * 32 + fk];
#pragma unroll
        for (int i = 0; i < 4; i++)
#pragma unroll
            for (int j = 0; j < 4; j++)
                accS[i][j] = __builtin_amdgcn_mfma_f32_16x16x32_bf16(
                    af[i], bff[j], accS[i][j], 0, 0, 0);
        __syncthreads();
    }

    const float scale = 0.03125f;   // 1/sqrt(1024)
    const int col   = lane & 15;
    const int rbase = (lane >> 4) * 4;
    const float* ub = u + (size_t)b * T_ + i0;
    const float* vb = v + (size_t)b * T_ + j0;

    float vval[4];
#pragma unroll
    for (int j = 0; j < 4; j++) vval[j] = vb[wn + j * 16 + col];
    float uval[4][4];
#pragma unroll
    for (int i = 0; i < 4; i++)
#pragma unroll
        for (int r = 0; r < 4; r++) uval[i][r] = ub[wm + i * 16 + rbase + r];

    float l_part[4][4], A_part[4][4];
#pragma unroll
    for (int i = 0; i < 4; i++)
#pragma unroll
        for (int r = 0; r < 4; r++) { l_part[i][r] = 0.f; A_part[i][r] = 0.f; }

    const unsigned short* Gt =
        gb + (((size_t)(b * 8 + i0b) * 8 + j0b) << 14) + tid * 8;
#pragma unroll
    for (int c = 0; c < 8; ++c) {
        u16x8 gv = *(const u16x8*)(Gt + (size_t)c * 2048);
        const int i = c >> 1;
#pragma unroll
        for (int e = 0; e < 8; ++e) {
            const int f  = c * 8 + e;
            const int jj = (f >> 2) & 3;
            const int r  = f & 3;
            float p = __expf((accS[i][jj][r] + uval[i][r] + vval[jj]) * scale);
            float g = bf2f(gv[e]);
            l_part[i][r] += p;
            A_part[i][r] += p * g;
        }
    }

#pragma unroll
    for (int m = 1; m < 16; m <<= 1) {
#pragma unroll
        for (int i = 0; i < 4; i++)
#pragma unroll
            for (int r = 0; r < 4; r++) {
                l_part[i][r] += __shfl_xor(l_part[i][r], m);
                A_part[i][r] += __shfl_xor(A_part[i][r], m);
            }
    }

    if ((lane & 15) == 0) {
        const int half = wave & 1;
        const size_t base =
            ((((size_t)b * 8 + i0b) * 8 + j0b) * 2 + half) * 128;
        float* lrow = lpart + base;
        float* Arow = Apart + base;
#pragma unroll
        for (int i = 0; i < 4; i++)
#pragma unroll
            for (int r = 0; r < 4; r++) {
                int row = wm + i * 16 + rbase + r;
                lrow[row] = l_part[i][r];
                Arow[row] = A_part[i][r];
            }
    }

    // ---- last-block finalize for this b ----
    __threadfence();                       // release partial stores
    if (tid == 0) lastflag = (atomicAdd(&ctr[b], 1) == 63);
    __syncthreads();
    if (lastflag) {
        __threadfence();                   // acquire all partials for b
        float s = 0.f;
#pragma unroll
        for (int p = 0; p < 4; ++p) {
            const int rg = tid + p * 256;
            const int ib = rg >> 7, row = rg & 127;
            const size_t base2 = ((size_t)b * 8 + ib) * 2048 + row;
            float lsum = 0.f, Asum = 0.f;
#pragma unroll
            for (int t = 0; t < 16; ++t) {
                lsum += lpart[base2 + (size_t)t * 128];
                Asum += Apart[base2 + (size_t)t * 128];
            }
            s += Asum / lsum;
        }
#pragma unroll
        for (int off = 32; off; off >>= 1) s += __shfl_down(s, off);
        float* fs = (float*)Ks;            // LDS free after K-loop
        if (lane == 0) fs[wave] = s;
        __syncthreads();
        if (tid == 0) out[b] = fs[0] + fs[1] + fs[2] + fs[3] + bfc[0];
    }
}

extern "C" void kernel_launch(void* const* d_in, const int* in_sizes, int n_in,
                              void* d_out, int out_size, void* d_ws, size_t ws_size,
                              hipStream_t stream) {
    const float* x   = (const float*)d_in[0];
    const float* Wq  = (const float*)d_in[1];
    const float* bq  = (const float*)d_in[2];
    const float* Wk  = (const float*)d_in[3];
    const float* bk  = (const float*)d_in[4];
    const float* Wv  = (const float*)d_in[5];
    const float* bv  = (const float*)d_in[6];
    const float* Wfc = (const float*)d_in[7];
    const float* bfc = (const float*)d_in[8];
    float* out = (float*)d_out;

    // workspace layout (~110.5 MB), every byte written before read each call:
    char* ws = (char*)d_ws;
    unsigned short* xb    = (unsigned short*)ws;                   // 32 MB
    unsigned short* wqb   = xb   + (size_t)B_ * T_ * D_;           // 2 MB
    unsigned short* wkb   = wqb  + (size_t)D_ * D_;                // 2 MB
    unsigned short* wvb   = wkb  + (size_t)D_ * D_;                // 2 MB
    unsigned short* wfcb  = wvb  + (size_t)D_ * D_;                // 2 MB
    unsigned short* ntb   = wfcb + (size_t)D_ * D_;                // 2 MB
    unsigned short* mb    = ntb  + (size_t)D_ * D_;                // 2 MB
    unsigned short* pb    = mb   + (size_t)D_ * D_;                // 32 MB
    unsigned short* gbuf  = pb   + (size_t)B_ * T_ * D_;           // 32 MB
    float*          w1    = (float*)(gbuf + (size_t)B_ * T_ * T_); // 4 KB
    float*          w2    = w1 + D_;                               // 4 KB
    float*          cvec  = w2 + D_;                               // 4 KB
    float*          bkbq  = cvec + D_;                             // 16 B
    float*          u     = bkbq + 4;                              // 64 KB
    float*          v     = u + (size_t)B_ * T_;                   // 64 KB
    float*          lpart = v + (size_t)B_ * T_;                   // 1 MB
    float*          Apart = lpart + (size_t)B_ * 8 * 8 * 2 * 128;  // 1 MB
    int*            ctr   = (int*)(Apart + (size_t)B_ * 8 * 8 * 2 * 128); // 64 B

    prep      <<<dim3(9344),      256, 0, stream>>>(
        x, Wq, Wk, Wv, Wfc, bq, bk, bv,
        xb, wqb, wkb, wvb, wfcb, ntb, mb, w1, w2, cvec, bkbq, ctr);
    pg_gemm   <<<dim3(6144),      256, 0, stream>>>(
        xb, ntb, mb, cvec, w1, w2, bkbq, pb, gbuf, u, v);
    score_attn<<<dim3(8, 8, 16),  256, 0, stream>>>(
        pb, xb, gbuf, u, v, lpart, Apart, ctr, bfc, out);
}

// Round 10
// 371.906 us; speedup vs baseline: 1.6066x; 1.6066x over previous
//
#include <hip/hip_runtime.h>
#include <hip/hip_bf16.h>

// Problem constants
#define B_ 16
#define T_ 1024
#define D_ 1024

using frag8  = __attribute__((ext_vector_type(8))) short;   // 8 bf16 (4 VGPRs)
using f32x4  = __attribute__((ext_vector_type(4))) float;   // 4 fp32 acc
using u16x8  = __attribute__((ext_vector_type(8))) unsigned short; // 16B chunk

__device__ inline unsigned short f2bf(float f) {
    union { float f; unsigned u; } v; v.f = f;
    unsigned r = v.u + 0x7FFF + ((v.u >> 16) & 1);   // round-nearest-even
    return (unsigned short)(r >> 16);
}
__device__ inline float bf2f(unsigned short u) {
    union { unsigned u; float f; } v; v.u = ((unsigned)u) << 16;
    return v.f;
}

// ---------------------------------------------------------------------------
// L1 "prep" (grid 5248): all input-only work, duration-matched cohorts.
//  [0,128)      small weight-product GEMMs reading fp32 DIRECTLY
//               (float4 loads + f2bf + ds_write_b64 staging — vectorized):
//                 z=0: NT[f][e]=sum_d Wq[f][d]Wk[e][d] -> ntb
//                 z=1: M [q][e]=sum_d Wfc[q][d]Wv[e][d] -> mb
//               (~25 us each, covered by the streaming cohorts below)
//  [128,1152)   wvec: w1=Wk·bq, w2=Wq·bk, cvec=Wfc·bv, bkbq=bk·bq
//               (y==3 block 0 also zeroes the 16 finalize counters)
//  [1152,5248)  fused x cast + u/v row dots (fp32 x, single pass)
// ---------------------------------------------------------------------------
__global__ __launch_bounds__(256)
void prep(const float* __restrict__ x,
          const float* __restrict__ Wq, const float* __restrict__ Wk,
          const float* __restrict__ Wv, const float* __restrict__ Wfc,
          const float* __restrict__ bq, const float* __restrict__ bk,
          const float* __restrict__ bv,
          unsigned short* __restrict__ xb,
          unsigned short* __restrict__ ntb, unsigned short* __restrict__ mb,
          float* __restrict__ w1, float* __restrict__ w2,
          float* __restrict__ cvec, float* __restrict__ bkbq,
          float* __restrict__ u, float* __restrict__ v,
          int* __restrict__ ctr) {
    __shared__ __align__(16) unsigned char smem[16384];
    const int bx  = blockIdx.x;
    const int tid = threadIdx.x, lane = tid & 63, wave = tid >> 6;

    if (bx < 128) {
        // ---- small GEMM, fp32 inputs, vectorized convert-in-staging ----
        unsigned short* As = (unsigned short*)smem;   // 8 KB
        unsigned short* Bs = As + 4096;               // 8 KB
        const int z = bx >> 6, rem = bx & 63;
        const int n0 = (rem & 7) * 128, m0 = (rem >> 3) * 128;
        const float* A  = z ? Wfc : Wq;
        const float* Bm = z ? Wv  : Wk;
        unsigned short* out = z ? mb : ntb;

        const int wm = (wave >> 1) * 64, wn = (wave & 1) * 64;
        f32x4 acc[4][4];
#pragma unroll
        for (int i = 0; i < 4; i++)
#pragma unroll
            for (int j = 0; j < 4; j++) acc[i][j] = (f32x4){0.f, 0.f, 0.f, 0.f};

        const int srow8 = tid >> 3;        // 0..31 (row within 32-row pass)
        const int kq    = (tid & 7) * 4;   // float4 k-offset
        const int fr = lane & 15, fk = (lane >> 4) * 8;

        for (int k0 = 0; k0 < D_; k0 += 32) {
#pragma unroll
            for (int p = 0; p < 4; ++p) {
                const int m = p * 32 + srow8;
                float4 a = *(const float4*)&A [(size_t)(m0 + m) * D_ + k0 + kq];
                float4 b = *(const float4*)&Bm[(size_t)(n0 + m) * D_ + k0 + kq];
                ushort4 ca, cb;
                ca.x = f2bf(a.x); ca.y = f2bf(a.y); ca.z = f2bf(a.z); ca.w = f2bf(a.w);
                cb.x = f2bf(b.x); cb.y = f2bf(b.y); cb.z = f2bf(b.z); cb.w = f2bf(b.w);
                *(ushort4*)&As[m * 32 + kq] = ca;
                *(ushort4*)&Bs[m * 32 + kq] = cb;
            }
            __syncthreads();
            frag8 af[4], bff[4];
#pragma unroll
            for (int t = 0; t < 4; ++t) {
                af[t]  = *(const frag8*)&As[(wm + t * 16 + fr) * 32 + fk];
                bff[t] = *(const frag8*)&Bs[(wn + t * 16 + fr) * 32 + fk];
            }
#pragma unroll
            for (int i = 0; i < 4; i++)
#pragma unroll
                for (int j = 0; j < 4; j++)
                    acc[i][j] = __builtin_amdgcn_mfma_f32_16x16x32_bf16(
                        af[i], bff[j], acc[i][j], 0, 0, 0);
            __syncthreads();
        }
        const int col = lane & 15, rbase = (lane >> 4) * 4;
#pragma unroll
        for (int i = 0; i < 4; i++)
#pragma unroll
            for (int j = 0; j < 4; j++) {
                int gn = n0 + wn + j * 16 + col;
#pragma unroll
                for (int r = 0; r < 4; r++) {
                    int gm = m0 + wm + i * 16 + rbase + r;
                    out[(size_t)gm * D_ + gn] = f2bf(acc[i][j][r]);
                }
            }
        return;
    }
    if (bx < 1152) {
        // ---- wvec ----
        const int b2 = bx - 128, y = b2 >> 8, xblk = b2 & 255;
        float* sm = (float*)smem;
        if (y == 3) {
            if (xblk != 0) return;
            if (tid < B_) ctr[tid] = 0;           // zero finalize counters
            float s = 0.f;
#pragma unroll
            for (int p = 0; p < 4; ++p) { int i = tid + p * 256; s += bk[i] * bq[i]; }
#pragma unroll
            for (int off = 32; off; off >>= 1) s += __shfl_down(s, off);
            if (lane == 0) sm[wave] = s;
            __syncthreads();
            if (tid == 0) bkbq[0] = sm[0] + sm[1] + sm[2] + sm[3];
            return;
        }
        const float* Wsrc; const float* bvv; float* outp;
        if (y == 0)      { Wsrc = Wk;  bvv = bq; outp = w1; }
        else if (y == 1) { Wsrc = Wq;  bvv = bk; outp = w2; }
        else             { Wsrc = Wfc; bvv = bv; outp = cvec; }
        const int row = xblk * 4 + wave;
        const float* r = Wsrc + (size_t)row * D_;
        float s = 0.f;
#pragma unroll
        for (int it = 0; it < 4; ++it) {
            float4 a = *(const float4*)&r[it * 256 + lane * 4];
            float4 b = *(const float4*)&bvv[it * 256 + lane * 4];
            s += a.x * b.x + a.y * b.y + a.z * b.z + a.w * b.w;
        }
#pragma unroll
        for (int off = 32; off; off >>= 1) s += __shfl_down(s, off);
        if (lane == 0) outp[row] = s;
        return;
    }
    // ---- fused x cast + uv dots (4 rows/block, 1 row/wave) ----
    {
        float* s1 = (float*)smem;         // 4 KB
        float* s2 = s1 + 1024;            // 4 KB
#pragma unroll
        for (int p = 0; p < 4; ++p) {
            int i = tid + p * 256;
            s1[i] = w1[i]; s2[i] = w2[i];
        }
        __syncthreads();
        const int row = (bx - 1152) * 4 + wave;
        const float* xr = x + (size_t)row * D_;
        unsigned short* xo = xb + (size_t)row * D_;
        float du = 0.f, dv = 0.f;
#pragma unroll
        for (int k = 0; k < 4; ++k) {
            const int e0 = k * 256 + lane * 4;
            float4 a = *(const float4*)&xr[e0];
            ushort4 o;
            o.x = f2bf(a.x); o.y = f2bf(a.y); o.z = f2bf(a.z); o.w = f2bf(a.w);
            *(ushort4*)&xo[e0] = o;
            du += a.x * s1[e0] + a.y * s1[e0 + 1] + a.z * s1[e0 + 2] + a.w * s1[e0 + 3];
            dv += a.x * s2[e0] + a.y * s2[e0 + 1] + a.z * s2[e0 + 2] + a.w * s2[e0 + 3];
        }
#pragma unroll
        for (int off = 32; off; off >>= 1) {
            du += __shfl_down(du, off);
            dv += __shfl_down(dv, off);
        }
        if (lane == 0) { u[row] = du; v[row] = dv + bkbq[0]; }
    }
}

// ---------------------------------------------------------------------------
// L2: fused P/G GEMM (R8-proven).  A = xb (M=16384, K=1024, N=1024):
//  z=0: P[i][f] = x·NT^T -> pb (row-major bf16)
//  z=1: G[i][q] = x·M^T + c -> gbuf fragment-swizzled (16B chunks/thread)
// XCD swizzle: each XCD owns 16 m-blocks (4 MB of x, L2-resident).
// grid (8, 128, 2), linear = x + 8y + 1024z.
// ---------------------------------------------------------------------------
__global__ __launch_bounds__(256)
void pg_gemm(const unsigned short* __restrict__ xb,
             const unsigned short* __restrict__ ntb,
             const unsigned short* __restrict__ mb,
             const float* __restrict__ cvec,
             unsigned short* __restrict__ pb,
             unsigned short* __restrict__ gbuf) {
    __shared__ __align__(16) unsigned short As[128 * 32];
    __shared__ __align__(16) unsigned short Bs[128 * 32];

    const int l    = blockIdx.x + 8 * blockIdx.y + 1024 * blockIdx.z;
    const int xcd  = l & 7;
    const int idx  = l >> 3;            // 0..255
    const int mblk = xcd * 16 + (idx & 15);
    const int rest = idx >> 4;          // 0..15
    const int z    = rest >> 3;
    const int nblk = rest & 7;
    const int n0   = nblk * 128;
    const int m0   = mblk * 128;

    const unsigned short* Bm = z ? mb : ntb;

    const int tid = threadIdx.x, lane = tid & 63, wave = tid >> 6;
    const int wm = (wave >> 1) * 64, wn = (wave & 1) * 64;

    f32x4 acc[4][4];
#pragma unroll
    for (int i = 0; i < 4; i++)
#pragma unroll
        for (int j = 0; j < 4; j++) acc[i][j] = (f32x4){0.f, 0.f, 0.f, 0.f};

    const int srow = lane >> 2;
    const int sk   = (lane & 3) * 8;
    const int fr = lane & 15, fk = (lane >> 4) * 8;

    for (int k0 = 0; k0 < D_; k0 += 32) {
#pragma unroll
        for (int it = 0; it < 2; ++it) {
            const int rb = wave * 2 + it;
            const int r  = rb * 16 + srow;
            __builtin_amdgcn_global_load_lds(
                (const __attribute__((address_space(1))) unsigned int*)
                    (xb + (size_t)(m0 + r) * D_ + k0 + sk),
                (__attribute__((address_space(3))) unsigned int*)(As + rb * 512),
                16, 0, 0);
            __builtin_amdgcn_global_load_lds(
                (const __attribute__((address_space(1))) unsigned int*)
                    (Bm + (size_t)(n0 + r) * D_ + k0 + sk),
                (__attribute__((address_space(3))) unsigned int*)(Bs + rb * 512),
                16, 0, 0);
        }
        __syncthreads();

        frag8 af[4], bff[4];
#pragma unroll
        for (int t = 0; t < 4; ++t)
            af[t] = *(const frag8*)&As[(wm + t * 16 + fr) * 32 + fk];
#pragma unroll
        for (int t = 0; t < 4; ++t)
            bff[t] = *(const frag8*)&Bs[(wn + t * 16 + fr) * 32 + fk];
#pragma unroll
        for (int i = 0; i < 4; i++)
#pragma unroll
            for (int j = 0; j < 4; j++)
                acc[i][j] = __builtin_amdgcn_mfma_f32_16x16x32_bf16(
                    af[i], bff[j], acc[i][j], 0, 0, 0);
        __syncthreads();
    }

    const int col   = lane & 15;
    const int rbase = (lane >> 4) * 4;
    if (z == 0) {
#pragma unroll
        for (int i = 0; i < 4; i++) {
#pragma unroll
            for (int j = 0; j < 4; j++) {
                int gn = n0 + wn + j * 16 + col;
#pragma unroll
                for (int r = 0; r < 4; r++) {
                    int gm = m0 + wm + i * 16 + rbase + r;
                    pb[(size_t)gm * D_ + gn] = f2bf(acc[i][j][r]);
                }
            }
        }
    } else {
        float bb[4];
#pragma unroll
        for (int j = 0; j < 4; j++) bb[j] = cvec[n0 + wn + j * 16 + col];
        unsigned short* base = gbuf + ((size_t)(mblk * 8 + nblk) << 14) + tid * 8;
#pragma unroll
        for (int c = 0; c < 8; ++c) {
            const int i = c >> 1;
            u16x8 o;
#pragma unroll
            for (int e = 0; e < 8; ++e) {
                const int f  = c * 8 + e;
                const int jj = (f >> 2) & 3;
                const int r  = f & 3;
                o[e] = f2bf(acc[i][jj][r] + bb[jj]);
            }
            *(u16x8*)(base + (size_t)c * 2048) = o;
        }
    }
}

// ---------------------------------------------------------------------------
// L3: score + exp + G-weighted row reduction + LAST-BLOCK FINALIZE.
// S = P·x^T (+u_i+v_j), p = exp(S·scale); deterministic partial stores
// (each slot single-writer).  The 64th block of each b (device-scope
// counter) sums all partials in fixed order and writes out[b] — identical
// arithmetic regardless of which block finalizes.  grid (8,8,16).
// ---------------------------------------------------------------------------
__global__ __launch_bounds__(256)
void score_attn(const unsigned short* __restrict__ pbuf,
                const unsigned short* __restrict__ xb,
                const unsigned short* __restrict__ gb,
                const float* __restrict__ u, const float* __restrict__ v,
                float* __restrict__ lpart, float* __restrict__ Apart,
                int* __restrict__ ctr, const float* __restrict__ bfc,
                float* __restrict__ out) {
    __shared__ __align__(16) unsigned short Ks[128 * 32];
    __shared__ __align__(16) unsigned short Qs[128 * 32];
    __shared__ int lastflag;

    const int l   = blockIdx.x + 8 * blockIdx.y + 64 * blockIdx.z;
    const int xcd = l & 7;
    const int uix = l >> 3;            // 0..127
    const int i0b = uix >> 4;          // 0..7  (i0 outer)
    const int mid = uix & 15;
    const int b   = xcd * 2 + (mid >> 3);
    const int j0b = mid & 7;           // j0 inner
    const int i0 = i0b * 128, j0 = j0b * 128;

    const unsigned short* P = pbuf + ((size_t)b * T_ + i0) * D_;
    const unsigned short* X = xb   + ((size_t)b * T_ + j0) * D_;

    const int tid = threadIdx.x, lane = tid & 63, wave = tid >> 6;
    const int wm = (wave >> 1) * 64, wn = (wave & 1) * 64;

    f32x4 accS[4][4];
#pragma unroll
    for (int i = 0; i < 4; i++)
#pragma unroll
        for (int j = 0; j < 4; j++) accS[i][j] = (f32x4){0.f, 0.f, 0.f, 0.f};

    const int srow = lane >> 2;
    const int sk   = (lane & 3) * 8;
    const int fr = lane & 15, fk = (lane >> 4) * 8;

    for (int k0 = 0; k0 < D_; k0 += 32) {
#pragma unroll
        for (int it = 0; it < 2; ++it) {
            const int rb = wave * 2 + it;
            const int r  = rb * 16 + srow;
            __builtin_amdgcn_global_load_lds(
                (const __attribute__((address_space(1))) unsigned int*)
                    (P + (size_t)r * D_ + k0 + sk),
                (__attribute__((address_space(3))) unsigned int*)(Ks + rb * 512),
                16, 0, 0);
            __builtin_amdgcn_global_load_lds(
                (const __attribute__((address_space(1))) unsigned int*)
                    (X + (size_t)r * D_ + k0 + sk),
                (__attribute__((address_space(3))) unsigned int*)(Qs + rb * 512),
                16, 0, 0);
        }
        __syncthreads();

        frag8 af[4], bff[4];
#pragma unroll
        for (int t = 0; t < 4; ++t)
            af[t] = *(const frag8*)&Ks[(wm + t * 16 + fr) * 32 + fk];
#pragma unroll
        for (int t = 0; t < 4; ++t)
            bff[t] = *(const frag8*)&Qs[(wn + t * 16 + fr) * 32 + fk];
#pragma unroll
        for (int i = 0; i < 4; i++)
#pragma unroll
            for (int j = 0; j < 4; j++)
                accS[i][j] = __builtin_amdgcn_mfma_f32_16x16x32_bf16(
                    af[i], bff[j], accS[i][j], 0, 0, 0);
        __syncthreads();
    }

    const float scale = 0.03125f;   // 1/sqrt(1024)
    const int col   = lane & 15;
    const int rbase = (lane >> 4) * 4;
    const float* ub = u + (size_t)b * T_ + i0;
    const float* vb = v + (size_t)b * T_ + j0;

    float vval[4];
#pragma unroll
    for (int j = 0; j < 4; j++) vval[j] = vb[wn + j * 16 + col];
    float uval[4][4];
#pragma unroll
    for (int i = 0; i < 4; i++)
#pragma unroll
        for (int r = 0; r < 4; r++) uval[i][r] = ub[wm + i * 16 + rbase + r];

    float l_part[4][4], A_part[4][4];
#pragma unroll
    for (int i = 0; i < 4; i++)
#pragma unroll
        for (int r = 0; r < 4; r++) { l_part[i][r] = 0.f; A_part[i][r] = 0.f; }

    const unsigned short* Gt =
        gb + (((size_t)(b * 8 + i0b) * 8 + j0b) << 14) + tid * 8;
#pragma unroll
    for (int c = 0; c < 8; ++c) {
        u16x8 gv = *(const u16x8*)(Gt + (size_t)c * 2048);
        const int i = c >> 1;
#pragma unroll
        for (int e = 0; e < 8; ++e) {
            const int f  = c * 8 + e;
            const int jj = (f >> 2) & 3;
            const int r  = f & 3;
            float p = __expf((accS[i][jj][r] + uval[i][r] + vval[jj]) * scale);
            float g = bf2f(gv[e]);
            l_part[i][r] += p;
            A_part[i][r] += p * g;
        }
    }

#pragma unroll
    for (int m = 1; m < 16; m <<= 1) {
#pragma unroll
        for (int i = 0; i < 4; i++)
#pragma unroll
            for (int r = 0; r < 4; r++) {
                l_part[i][r] += __shfl_xor(l_part[i][r], m);
                A_part[i][r] += __shfl_xor(A_part[i][r], m);
            }
    }

    if ((lane & 15) == 0) {
        const int half = wave & 1;
        const size_t base =
            ((((size_t)b * 8 + i0b) * 8 + j0b) * 2 + half) * 128;
        float* lrow = lpart + base;
        float* Arow = Apart + base;
#pragma unroll
        for (int i = 0; i < 4; i++)
#pragma unroll
            for (int r = 0; r < 4; r++) {
                int row = wm + i * 16 + rbase + r;
                lrow[row] = l_part[i][r];
                Arow[row] = A_part[i][r];
            }
    }

    // ---- last-block finalize for this b ----
    __threadfence();                       // release partial stores
    if (tid == 0) lastflag = (atomicAdd(&ctr[b], 1) == 63);
    __syncthreads();
    if (lastflag) {
        __threadfence();                   // acquire all partials for b
        float s = 0.f;
#pragma unroll
        for (int p = 0; p < 4; ++p) {
            const int rg = tid + p * 256;
            const int ib = rg >> 7, row = rg & 127;
            const size_t base2 = ((size_t)b * 8 + ib) * 2048 + row;
            float lsum = 0.f, Asum = 0.f;
#pragma unroll
            for (int t = 0; t < 16; ++t) {
                lsum += lpart[base2 + (size_t)t * 128];
                Asum += Apart[base2 + (size_t)t * 128];
            }
            s += Asum / lsum;
        }
#pragma unroll
        for (int off = 32; off; off >>= 1) s += __shfl_down(s, off);
        float* fs = (float*)Ks;            // LDS free after K-loop
        if (lane == 0) fs[wave] = s;
        __syncthreads();
        if (tid == 0) out[b] = fs[0] + fs[1] + fs[2] + fs[3] + bfc[0];
    }
}

extern "C" void kernel_launch(void* const* d_in, const int* in_sizes, int n_in,
                              void* d_out, int out_size, void* d_ws, size_t ws_size,
                              hipStream_t stream) {
    const float* x   = (const float*)d_in[0];
    const float* Wq  = (const float*)d_in[1];
    const float* bq  = (const float*)d_in[2];
    const float* Wk  = (const float*)d_in[3];
    const float* bk  = (const float*)d_in[4];
    const float* Wv  = (const float*)d_in[5];
    const float* bv  = (const float*)d_in[6];
    const float* Wfc = (const float*)d_in[7];
    const float* bfc = (const float*)d_in[8];
    float* out = (float*)d_out;

    // workspace layout (~102.5 MB), every byte written before read each call:
    char* ws = (char*)d_ws;
    unsigned short* xb    = (unsigned short*)ws;                   // 32 MB
    unsigned short* ntb   = xb  + (size_t)B_ * T_ * D_;            // 2 MB
    unsigned short* mb    = ntb + (size_t)D_ * D_;                 // 2 MB
    unsigned short* pb    = mb  + (size_t)D_ * D_;                 // 32 MB
    unsigned short* gbuf  = pb  + (size_t)B_ * T_ * D_;            // 32 MB
    float*          w1    = (float*)(gbuf + (size_t)B_ * T_ * T_); // 4 KB
    float*          w2    = w1 + D_;                               // 4 KB
    float*          cvec  = w2 + D_;                               // 4 KB
    float*          bkbq  = cvec + D_;                             // 16 B
    float*          u     = bkbq + 4;                              // 64 KB
    float*          v     = u + (size_t)B_ * T_;                   // 64 KB
    float*          lpart = v + (size_t)B_ * T_;                   // 1 MB
    float*          Apart = lpart + (size_t)B_ * 8 * 8 * 2 * 128;  // 1 MB
    int*            ctr   = (int*)(Apart + (size_t)B_ * 8 * 8 * 2 * 128); // 64 B

    prep      <<<dim3(5248),      256, 0, stream>>>(
        x, Wq, Wk, Wv, Wfc, bq, bk, bv,
        xb, ntb, mb, w1, w2, cvec, bkbq, u, v, ctr);
    pg_gemm   <<<dim3(8, 128, 2), 256, 0, stream>>>(
        xb, ntb, mb, cvec, pb, gbuf);
    score_attn<<<dim3(8, 8, 16),  256, 0, stream>>>(
        pb, xb, gbuf, u, v, lpart, Apart, ctr, bfc, out);
}

// Round 11
// 319.523 us; speedup vs baseline: 1.8700x; 1.1639x over previous
//
#include <hip/hip_runtime.h>
#include <hip/hip_bf16.h>

// Problem constants
#define B_ 16
#define T_ 1024
#define D_ 1024

using frag8  = __attribute__((ext_vector_type(8))) short;   // 8 bf16 (4 VGPRs)
using f32x4  = __attribute__((ext_vector_type(4))) float;   // 4 fp32 acc
using u16x8  = __attribute__((ext_vector_type(8))) unsigned short; // 16B chunk

__device__ inline unsigned short f2bf(float f) {
    union { float f; unsigned u; } v; v.f = f;
    unsigned r = v.u + 0x7FFF + ((v.u >> 16) & 1);   // round-nearest-even
    return (unsigned short)(r >> 16);
}
__device__ inline float bf2f(unsigned short u) {
    union { unsigned u; float f; } v; v.u = ((unsigned)u) << 16;
    return v.f;
}

// ---------------------------------------------------------------------------
// L1 "prep" (grid 5248): input-only work, NO intra-launch dependencies.
//  [0,128)      small weight-product GEMMs reading fp32 DIRECTLY
//               (float4 loads + f2bf + vector LDS writes):
//                 z=0: NT[f][e]=sum_d Wq[f][d]Wk[e][d] -> ntb
//                 z=1: M [q][e]=sum_d Wfc[q][d]Wv[e][d] -> mb
//  [128,1152)   wvec: w1=Wk·bq, w2=Wq·bk, cvec=Wfc·bv, bkbq=bk·bq
//  [1152,5248)  x fp32 -> bf16 cast (pure streaming)
// ---------------------------------------------------------------------------
__global__ __launch_bounds__(256)
void prep(const float* __restrict__ x,
          const float* __restrict__ Wq, const float* __restrict__ Wk,
          const float* __restrict__ Wv, const float* __restrict__ Wfc,
          const float* __restrict__ bq, const float* __restrict__ bk,
          const float* __restrict__ bv,
          unsigned short* __restrict__ xb,
          unsigned short* __restrict__ ntb, unsigned short* __restrict__ mb,
          float* __restrict__ w1, float* __restrict__ w2,
          float* __restrict__ cvec, float* __restrict__ bkbq) {
    __shared__ __align__(16) unsigned char smem[16384];
    const int bx  = blockIdx.x;
    const int tid = threadIdx.x, lane = tid & 63, wave = tid >> 6;

    if (bx < 128) {
        // ---- small GEMM, fp32 inputs, vectorized convert-in-staging ----
        unsigned short* As = (unsigned short*)smem;   // 8 KB
        unsigned short* Bs = As + 4096;               // 8 KB
        const int z = bx >> 6, rem = bx & 63;
        const int n0 = (rem & 7) * 128, m0 = (rem >> 3) * 128;
        const float* A  = z ? Wfc : Wq;
        const float* Bm = z ? Wv  : Wk;
        unsigned short* out = z ? mb : ntb;

        const int wm = (wave >> 1) * 64, wn = (wave & 1) * 64;
        f32x4 acc[4][4];
#pragma unroll
        for (int i = 0; i < 4; i++)
#pragma unroll
            for (int j = 0; j < 4; j++) acc[i][j] = (f32x4){0.f, 0.f, 0.f, 0.f};

        const int srow8 = tid >> 3;        // 0..31 (row within 32-row pass)
        const int kq    = (tid & 7) * 4;   // float4 k-offset
        const int fr = lane & 15, fk = (lane >> 4) * 8;

        for (int k0 = 0; k0 < D_; k0 += 32) {
#pragma unroll
            for (int p = 0; p < 4; ++p) {
                const int m = p * 32 + srow8;
                float4 a = *(const float4*)&A [(size_t)(m0 + m) * D_ + k0 + kq];
                float4 b = *(const float4*)&Bm[(size_t)(n0 + m) * D_ + k0 + kq];
                ushort4 ca, cb;
                ca.x = f2bf(a.x); ca.y = f2bf(a.y); ca.z = f2bf(a.z); ca.w = f2bf(a.w);
                cb.x = f2bf(b.x); cb.y = f2bf(b.y); cb.z = f2bf(b.z); cb.w = f2bf(b.w);
                *(ushort4*)&As[m * 32 + kq] = ca;
                *(ushort4*)&Bs[m * 32 + kq] = cb;
            }
            __syncthreads();
            frag8 af[4], bff[4];
#pragma unroll
            for (int t = 0; t < 4; ++t) {
                af[t]  = *(const frag8*)&As[(wm + t * 16 + fr) * 32 + fk];
                bff[t] = *(const frag8*)&Bs[(wn + t * 16 + fr) * 32 + fk];
            }
#pragma unroll
            for (int i = 0; i < 4; i++)
#pragma unroll
                for (int j = 0; j < 4; j++)
                    acc[i][j] = __builtin_amdgcn_mfma_f32_16x16x32_bf16(
                        af[i], bff[j], acc[i][j], 0, 0, 0);
            __syncthreads();
        }
        const int col = lane & 15, rbase = (lane >> 4) * 4;
#pragma unroll
        for (int i = 0; i < 4; i++)
#pragma unroll
            for (int j = 0; j < 4; j++) {
                int gn = n0 + wn + j * 16 + col;
#pragma unroll
                for (int r = 0; r < 4; r++) {
                    int gm = m0 + wm + i * 16 + rbase + r;
                    out[(size_t)gm * D_ + gn] = f2bf(acc[i][j][r]);
                }
            }
        return;
    }
    if (bx < 1152) {
        // ---- wvec ----
        const int b2 = bx - 128, y = b2 >> 8, xblk = b2 & 255;
        float* sm = (float*)smem;
        if (y == 3) {
            if (xblk != 0) return;
            float s = 0.f;
#pragma unroll
            for (int p = 0; p < 4; ++p) { int i = tid + p * 256; s += bk[i] * bq[i]; }
#pragma unroll
            for (int off = 32; off; off >>= 1) s += __shfl_down(s, off);
            if (lane == 0) sm[wave] = s;
            __syncthreads();
            if (tid == 0) bkbq[0] = sm[0] + sm[1] + sm[2] + sm[3];
            return;
        }
        const float* Wsrc; const float* bvv; float* outp;
        if (y == 0)      { Wsrc = Wk;  bvv = bq; outp = w1; }
        else if (y == 1) { Wsrc = Wq;  bvv = bk; outp = w2; }
        else             { Wsrc = Wfc; bvv = bv; outp = cvec; }
        const int row = xblk * 4 + wave;
        const float* r = Wsrc + (size_t)row * D_;
        float s = 0.f;
#pragma unroll
        for (int it = 0; it < 4; ++it) {
            float4 a = *(const float4*)&r[it * 256 + lane * 4];
            float4 b = *(const float4*)&bvv[it * 256 + lane * 4];
            s += a.x * b.x + a.y * b.y + a.z * b.z + a.w * b.w;
        }
#pragma unroll
        for (int off = 32; off; off >>= 1) s += __shfl_down(s, off);
        if (lane == 0) outp[row] = s;
        return;
    }
    // ---- x cast: 4096 blocks x 1024 float4 each ----
    {
        const int blk = bx - 1152;
#pragma unroll
        for (int p = 0; p < 4; ++p) {
            int i = blk * 1024 + p * 256 + tid;
            float4 v = ((const float4*)x)[i];
            ushort4 o;
            o.x = f2bf(v.x); o.y = f2bf(v.y); o.z = f2bf(v.z); o.w = f2bf(v.w);
            ((ushort4*)xb)[i] = o;
        }
    }
}

// ---------------------------------------------------------------------------
// L2 (grid 3072): fused P/G GEMM + uv row-dots (uv inputs all from L1).
//  [0,2048): GEMM, A = xb (M=16384, K=1024, N=1024):
//   z=0: P[i][f] = x·NT^T -> pb (row-major bf16)
//   z=1: G[i][q] = x·M^T + c -> gbuf fragment-swizzled (16B chunks/thread)
//   XCD swizzle: each XCD owns 16 m-blocks (4 MB of x, L2-resident).
//  [2048,3072): uv — u[i]=x_i·w1, v[i]=x_i·w2+bkbq (bf16 xb, 4 rows/block).
// ---------------------------------------------------------------------------
__global__ __launch_bounds__(256)
void pg_gemm(const unsigned short* __restrict__ xb,
             const unsigned short* __restrict__ ntb,
             const unsigned short* __restrict__ mb,
             const float* __restrict__ cvec,
             const float* __restrict__ w1, const float* __restrict__ w2,
             const float* __restrict__ bkbq,
             unsigned short* __restrict__ pb,
             unsigned short* __restrict__ gbuf,
             float* __restrict__ u, float* __restrict__ v) {
    __shared__ __align__(16) unsigned char smem[16384];
    const int l   = blockIdx.x;
    const int tid = threadIdx.x, lane = tid & 63, wave = tid >> 6;

    if (l >= 2048) {
        // ---- uv path (reads bf16 xb + w1/w2, all produced by L1) ----
        float* s1 = (float*)smem;
        float* s2 = s1 + 1024;
#pragma unroll
        for (int p = 0; p < 4; ++p) {
            int i = tid + p * 256;
            s1[i] = w1[i]; s2[i] = w2[i];
        }
        __syncthreads();
        const int row = (l - 2048) * 4 + wave;
        const unsigned short* xr = xb + (size_t)row * D_;
        float du = 0.f, dv = 0.f;
#pragma unroll
        for (int it = 0; it < 2; ++it) {
            const int base = it * 512 + lane * 8;
            ushort4 a0 = *(const ushort4*)&xr[base];
            ushort4 a1 = *(const ushort4*)&xr[base + 4];
            float xv[8] = {bf2f(a0.x), bf2f(a0.y), bf2f(a0.z), bf2f(a0.w),
                           bf2f(a1.x), bf2f(a1.y), bf2f(a1.z), bf2f(a1.w)};
            float4 b0 = *(const float4*)&s1[base];
            float4 b1 = *(const float4*)&s1[base + 4];
            float4 c0 = *(const float4*)&s2[base];
            float4 c1 = *(const float4*)&s2[base + 4];
            du += xv[0]*b0.x + xv[1]*b0.y + xv[2]*b0.z + xv[3]*b0.w
                + xv[4]*b1.x + xv[5]*b1.y + xv[6]*b1.z + xv[7]*b1.w;
            dv += xv[0]*c0.x + xv[1]*c0.y + xv[2]*c0.z + xv[3]*c0.w
                + xv[4]*c1.x + xv[5]*c1.y + xv[6]*c1.z + xv[7]*c1.w;
        }
#pragma unroll
        for (int off = 32; off; off >>= 1) {
            du += __shfl_down(du, off);
            dv += __shfl_down(dv, off);
        }
        if (lane == 0) { u[row] = du; v[row] = dv + bkbq[0]; }
        return;
    }

    // ---- GEMM path ----
    unsigned short* As = (unsigned short*)smem;
    unsigned short* Bs = As + 4096;

    const int xcd  = l & 7;
    const int idx  = l >> 3;            // 0..255
    const int mblk = xcd * 16 + (idx & 15);
    const int rest = idx >> 4;          // 0..15
    const int z    = rest >> 3;
    const int nblk = rest & 7;
    const int n0   = nblk * 128;
    const int m0   = mblk * 128;

    const unsigned short* Bm = z ? mb : ntb;
    const int wm = (wave >> 1) * 64, wn = (wave & 1) * 64;

    f32x4 acc[4][4];
#pragma unroll
    for (int i = 0; i < 4; i++)
#pragma unroll
        for (int j = 0; j < 4; j++) acc[i][j] = (f32x4){0.f, 0.f, 0.f, 0.f};

    const int srow = lane >> 2;
    const int sk   = (lane & 3) * 8;
    const int fr = lane & 15, fk = (lane >> 4) * 8;

    for (int k0 = 0; k0 < D_; k0 += 32) {
#pragma unroll
        for (int it = 0; it < 2; ++it) {
            const int rb = wave * 2 + it;
            const int r  = rb * 16 + srow;
            __builtin_amdgcn_global_load_lds(
                (const __attribute__((address_space(1))) unsigned int*)
                    (xb + (size_t)(m0 + r) * D_ + k0 + sk),
                (__attribute__((address_space(3))) unsigned int*)(As + rb * 512),
                16, 0, 0);
            __builtin_amdgcn_global_load_lds(
                (const __attribute__((address_space(1))) unsigned int*)
                    (Bm + (size_t)(n0 + r) * D_ + k0 + sk),
                (__attribute__((address_space(3))) unsigned int*)(Bs + rb * 512),
                16, 0, 0);
        }
        __syncthreads();

        frag8 af[4], bff[4];
#pragma unroll
        for (int t = 0; t < 4; ++t)
            af[t] = *(const frag8*)&As[(wm + t * 16 + fr) * 32 + fk];
#pragma unroll
        for (int t = 0; t < 4; ++t)
            bff[t] = *(const frag8*)&Bs[(wn + t * 16 + fr) * 32 + fk];
#pragma unroll
        for (int i = 0; i < 4; i++)
#pragma unroll
            for (int j = 0; j < 4; j++)
                acc[i][j] = __builtin_amdgcn_mfma_f32_16x16x32_bf16(
                    af[i], bff[j], acc[i][j], 0, 0, 0);
        __syncthreads();
    }

    const int col   = lane & 15;
    const int rbase = (lane >> 4) * 4;
    if (z == 0) {
#pragma unroll
        for (int i = 0; i < 4; i++) {
#pragma unroll
            for (int j = 0; j < 4; j++) {
                int gn = n0 + wn + j * 16 + col;
#pragma unroll
                for (int r = 0; r < 4; r++) {
                    int gm = m0 + wm + i * 16 + rbase + r;
                    pb[(size_t)gm * D_ + gn] = f2bf(acc[i][j][r]);
                }
            }
        }
    } else {
        float bb[4];
#pragma unroll
        for (int j = 0; j < 4; j++) bb[j] = cvec[n0 + wn + j * 16 + col];
        unsigned short* base = gbuf + ((size_t)(mblk * 8 + nblk) << 14) + tid * 8;
#pragma unroll
        for (int c = 0; c < 8; ++c) {
            const int i = c >> 1;
            u16x8 o;
#pragma unroll
            for (int e = 0; e < 8; ++e) {
                const int f  = c * 8 + e;
                const int jj = (f >> 2) & 3;
                const int r  = f & 3;
                o[e] = f2bf(acc[i][jj][r] + bb[jj]);
            }
            *(u16x8*)(base + (size_t)c * 2048) = o;
        }
    }
}

// ---------------------------------------------------------------------------
// L3: score + exp + G-weighted row reduction — DETERMINISTIC, fence-free.
// S[i][j] = sum_f P[b·T+i][f]·x[b·T+j][f] + u[b·T+i] + v[b·T+j]
// p = exp(S*scale).  G read from fragment-swizzled gbuf (8 b128 loads/lane).
// Partial stores: lpart/Apart[(((b*8+i0b)*8+j0b)*2+half)*128+row], each slot
// written exactly once.  grid (8,8,16) block 256, XCD swizzle as before.
// ---------------------------------------------------------------------------
__global__ __launch_bounds__(256)
void score_attn(const unsigned short* __restrict__ pbuf,
                const unsigned short* __restrict__ xb,
                const unsigned short* __restrict__ gb,
                const float* __restrict__ u, const float* __restrict__ v,
                float* __restrict__ lpart, float* __restrict__ Apart) {
    __shared__ __align__(16) unsigned short Ks[128 * 32];
    __shared__ __align__(16) unsigned short Qs[128 * 32];

    const int l   = blockIdx.x + 8 * blockIdx.y + 64 * blockIdx.z;
    const int xcd = l & 7;
    const int uix = l >> 3;            // 0..127
    const int i0b = uix >> 4;          // 0..7  (i0 outer)
    const int mid = uix & 15;
    const int b   = xcd * 2 + (mid >> 3);
    const int j0b = mid & 7;           // j0 inner
    const int i0 = i0b * 128, j0 = j0b * 128;

    const unsigned short* P = pbuf + ((size_t)b * T_ + i0) * D_;
    const unsigned short* X = xb   + ((size_t)b * T_ + j0) * D_;

    const int tid = threadIdx.x, lane = tid & 63, wave = tid >> 6;
    const int wm = (wave >> 1) * 64, wn = (wave & 1) * 64;

    f32x4 accS[4][4];
#pragma unroll
    for (int i = 0; i < 4; i++)
#pragma unroll
        for (int j = 0; j < 4; j++) accS[i][j] = (f32x4){0.f, 0.f, 0.f, 0.f};

    const int srow = lane >> 2;
    const int sk   = (lane & 3) * 8;
    const int fr = lane & 15, fk = (lane >> 4) * 8;

    for (int k0 = 0; k0 < D_; k0 += 32) {
#pragma unroll
        for (int it = 0; it < 2; ++it) {
            const int rb = wave * 2 + it;
            const int r  = rb * 16 + srow;
            __builtin_amdgcn_global_load_lds(
                (const __attribute__((address_space(1))) unsigned int*)
                    (P + (size_t)r * D_ + k0 + sk),
                (__attribute__((address_space(3))) unsigned int*)(Ks + rb * 512),
                16, 0, 0);
            __builtin_amdgcn_global_load_lds(
                (const __attribute__((address_space(1))) unsigned int*)
                    (X + (size_t)r * D_ + k0 + sk),
                (__attribute__((address_space(3))) unsigned int*)(Qs + rb * 512),
                16, 0, 0);
        }
        __syncthreads();

        frag8 af[4], bff[4];
#pragma unroll
        for (int t = 0; t < 4; ++t)
            af[t] = *(const frag8*)&Ks[(wm + t * 16 + fr) * 32 + fk];
#pragma unroll
        for (int t = 0; t < 4; ++t)
            bff[t] = *(const frag8*)&Qs[(wn + t * 16 + fr) * 32 + fk];
#pragma unroll
        for (int i = 0; i < 4; i++)
#pragma unroll
            for (int j = 0; j < 4; j++)
                accS[i][j] = __builtin_amdgcn_mfma_f32_16x16x32_bf16(
                    af[i], bff[j], accS[i][j], 0, 0, 0);
        __syncthreads();
    }

    const float scale = 0.03125f;   // 1/sqrt(1024)
    const int col   = lane & 15;
    const int rbase = (lane >> 4) * 4;
    const float* ub = u + (size_t)b * T_ + i0;
    const float* vb = v + (size_t)b * T_ + j0;

    float vval[4];
#pragma unroll
    for (int j = 0; j < 4; j++) vval[j] = vb[wn + j * 16 + col];
    float uval[4][4];
#pragma unroll
    for (int i = 0; i < 4; i++)
#pragma unroll
        for (int r = 0; r < 4; r++) uval[i][r] = ub[wm + i * 16 + rbase + r];

    float l_part[4][4], A_part[4][4];
#pragma unroll
    for (int i = 0; i < 4; i++)
#pragma unroll
        for (int r = 0; r < 4; r++) { l_part[i][r] = 0.f; A_part[i][r] = 0.f; }

    const unsigned short* Gt =
        gb + (((size_t)(b * 8 + i0b) * 8 + j0b) << 14) + tid * 8;
#pragma unroll
    for (int c = 0; c < 8; ++c) {
        u16x8 gv = *(const u16x8*)(Gt + (size_t)c * 2048);
        const int i = c >> 1;
#pragma unroll
        for (int e = 0; e < 8; ++e) {
            const int f  = c * 8 + e;
            const int jj = (f >> 2) & 3;
            const int r  = f & 3;
            float p = __expf((accS[i][jj][r] + uval[i][r] + vval[jj]) * scale);
            float g = bf2f(gv[e]);
            l_part[i][r] += p;
            A_part[i][r] += p * g;
        }
    }

#pragma unroll
    for (int m = 1; m < 16; m <<= 1) {
#pragma unroll
        for (int i = 0; i < 4; i++)
#pragma unroll
            for (int r = 0; r < 4; r++) {
                l_part[i][r] += __shfl_xor(l_part[i][r], m);
                A_part[i][r] += __shfl_xor(A_part[i][r], m);
            }
    }

    if ((lane & 15) == 0) {
        const int half = wave & 1;     // wn half: cols 0..63 vs 64..127
        const size_t base =
            ((((size_t)b * 8 + i0b) * 8 + j0b) * 2 + half) * 128;
        float* lrow = lpart + base;
        float* Arow = Apart + base;
#pragma unroll
        for (int i = 0; i < 4; i++)
#pragma unroll
            for (int r = 0; r < 4; r++) {
                int row = wm + i * 16 + rbase + r;
                lrow[row] = l_part[i][r];
                Arow[row] = A_part[i][r];
            }
    }
}

// ---------------------------------------------------------------------------
// L4: finalize — out[b] = bfc + sum_i (sum_t Apart)/(sum_t lpart).
// Fixed summation order -> bit-deterministic.  grid (16) block 256.
// ---------------------------------------------------------------------------
__global__ __launch_bounds__(256)
void finalize(const float* __restrict__ lpart, const float* __restrict__ Apart,
              const float* __restrict__ bfc, float* __restrict__ out) {
    const int b = blockIdx.x;
    const int tid = threadIdx.x, lane = tid & 63, wave = tid >> 6;
    float s = 0.f;
#pragma unroll
    for (int p = 0; p < 4; ++p) {
        const int rg = tid + p * 256;          // 0..1023 (row index within b)
        const int i0b = rg >> 7, row = rg & 127;
        const size_t base = ((size_t)b * 8 + i0b) * 2048 + row;
        float lsum = 0.f, Asum = 0.f;
#pragma unroll
        for (int t = 0; t < 16; ++t) {         // j0b*2 + half, fixed order
            lsum += lpart[base + (size_t)t * 128];
            Asum += Apart[base + (size_t)t * 128];
        }
        s += Asum / lsum;
    }
#pragma unroll
    for (int off = 32; off; off >>= 1) s += __shfl_down(s, off);
    __shared__ float ws_[4];
    if (lane == 0) ws_[wave] = s;
    __syncthreads();
    if (tid == 0) out[b] = ws_[0] + ws_[1] + ws_[2] + ws_[3] + bfc[0];
}

extern "C" void kernel_launch(void* const* d_in, const int* in_sizes, int n_in,
                              void* d_out, int out_size, void* d_ws, size_t ws_size,
                              hipStream_t stream) {
    const float* x   = (const float*)d_in[0];
    const float* Wq  = (const float*)d_in[1];
    const float* bq  = (const float*)d_in[2];
    const float* Wk  = (const float*)d_in[3];
    const float* bk  = (const float*)d_in[4];
    const float* Wv  = (const float*)d_in[5];
    const float* bv  = (const float*)d_in[6];
    const float* Wfc = (const float*)d_in[7];
    const float* bfc = (const float*)d_in[8];
    float* out = (float*)d_out;

    // workspace layout (~102.5 MB), every byte written before read each call:
    char* ws = (char*)d_ws;
    unsigned short* xb    = (unsigned short*)ws;                   // 32 MB
    unsigned short* ntb   = xb  + (size_t)B_ * T_ * D_;            // 2 MB
    unsigned short* mb    = ntb + (size_t)D_ * D_;                 // 2 MB
    unsigned short* pb    = mb  + (size_t)D_ * D_;                 // 32 MB
    unsigned short* gbuf  = pb  + (size_t)B_ * T_ * D_;            // 32 MB
    float*          w1    = (float*)(gbuf + (size_t)B_ * T_ * T_); // 4 KB
    float*          w2    = w1 + D_;                               // 4 KB
    float*          cvec  = w2 + D_;                               // 4 KB
    float*          bkbq  = cvec + D_;                             // 16 B
    float*          u     = bkbq + 4;                              // 64 KB
    float*          v     = u + (size_t)B_ * T_;                   // 64 KB
    float*          lpart = v + (size_t)B_ * T_;                   // 1 MB
    float*          Apart = lpart + (size_t)B_ * 8 * 8 * 2 * 128;  // 1 MB

    prep      <<<dim3(5248),      256, 0, stream>>>(
        x, Wq, Wk, Wv, Wfc, bq, bk, bv, xb, ntb, mb, w1, w2, cvec, bkbq);
    pg_gemm   <<<dim3(3072),      256, 0, stream>>>(
        xb, ntb, mb, cvec, w1, w2, bkbq, pb, gbuf, u, v);
    score_attn<<<dim3(8, 8, 16),  256, 0, stream>>>(
        pb, xb, gbuf, u, v, lpart, Apart);
    finalize  <<<dim3(B_),        256, 0, stream>>>(lpart, Apart, bfc, out);
}